// Round 1
// baseline (316.577 us; speedup 1.0000x reference)
//
#include <hip/hip_runtime.h>
#include <math.h>

#define T_TOK 2048
#define H_DIM 2048
#define V_DIM 32000
#define NE    16

typedef float fvec4 __attribute__((ext_vector_type(4)));

// ws layout:
//   scores: NE * T_TOK floats (transposed: scores[e*T_TOK + t]) = 128 KB
#define WS_SCORES(ws)  ((float*)(ws))

// ---------------------------------------------------------------------------
// Fused kernel: one block (256 thr) per token.
//  Phase 1 (gate): float4 dot products vs all 16 expert gate rows, wave
//    shuffle-reduce, LDS combine, thread-0 softmax + top-2 (strict > scan,
//    lowest index wins ties = jax top_k semantics). Weights/indices -> LDS.
//  Phase 2 (bias stream): whole block streams the token's V row.
//    Row base addresses are wave-uniform (scalarized); weights in registers.
//    NT stores keep the 262 MB write stream from evicting the 2 MB
//    expert_biases working set out of L2.
// Grid = 2048 blocks = exactly 8 blocks/CU, uniform work, no tail.
// ---------------------------------------------------------------------------
__global__ __launch_bounds__(256) void fused_kernel(const float4* __restrict__ hs,
                                                    const float4* __restrict__ gw,
                                                    const float4* __restrict__ eb,
                                                    float* __restrict__ scores,
                                                    float4* __restrict__ out)
{
    const int t   = blockIdx.x;
    const int tid = threadIdx.x;
    const int H4  = H_DIM / 4;   // 512
    const int V4  = V_DIM / 4;   // 8000

    // ---------------- gate ----------------
    float acc[NE];
#pragma unroll
    for (int e = 0; e < NE; ++e) acc[e] = 0.f;

    const float4* hrow = hs + (size_t)t * H4;
#pragma unroll
    for (int i = tid; i < H4; i += 256) {     // 2 iterations
        float4 x = hrow[i];
#pragma unroll
        for (int e = 0; e < NE; ++e) {
            float4 g = gw[e * H4 + i];
            acc[e] += x.x * g.x + x.y * g.y + x.z * g.z + x.w * g.w;
        }
    }

#pragma unroll
    for (int e = 0; e < NE; ++e) {
        float v = acc[e];
#pragma unroll
        for (int off = 32; off > 0; off >>= 1) v += __shfl_down(v, off, 64);
        acc[e] = v;
    }

    __shared__ float partial[4][NE];
    __shared__ float probs[NE];
    __shared__ float wsel[2];
    __shared__ int   isel[2];

    const int wave = tid >> 6, lane = tid & 63;
    if (lane == 0) {
#pragma unroll
        for (int e = 0; e < NE; ++e) partial[wave][e] = acc[e];
    }
    __syncthreads();

    if (tid == 0) {
        float logits[NE];
        float m = -INFINITY;
#pragma unroll
        for (int e = 0; e < NE; ++e) {
            logits[e] = partial[0][e] + partial[1][e] + partial[2][e] + partial[3][e];
            m = fmaxf(m, logits[e]);
        }
        float ex[NE];
        float Z = 0.f;
#pragma unroll
        for (int e = 0; e < NE; ++e) { ex[e] = expf(logits[e] - m); Z += ex[e]; }
        float invZ = 1.f / Z;
#pragma unroll
        for (int e = 0; e < NE; ++e) probs[e] = ex[e] * invZ;

        // top-2, strict > ascending scan => lowest index wins ties (jax semantics)
        int i0 = 0; float l0 = logits[0];
#pragma unroll
        for (int e = 1; e < NE; ++e) if (logits[e] > l0) { l0 = logits[e]; i0 = e; }
        int i1 = -1; float l1 = -INFINITY;
#pragma unroll
        for (int e = 0; e < NE; ++e) if (e != i0 && logits[e] > l1) { l1 = logits[e]; i1 = e; }

        float e0 = ex[i0], e1 = ex[i1];
        float inv = 1.f / (e0 + e1);
        wsel[0] = e0 * inv; wsel[1] = e1 * inv;
        isel[0] = i0; isel[1] = i1;
    }
    __syncthreads();

    if (tid < NE)
        scores[tid * T_TOK + t] = probs[tid];

    // ---------------- bias stream ----------------
    const float  w0 = wsel[0], w1 = wsel[1];
    const float4* r0 = eb + (size_t)isel[0] * V4;   // wave-uniform -> SGPR base
    const float4* r1 = eb + (size_t)isel[1] * V4;
    float4* orow = out + (size_t)t * V4;

    // 8000 = 31*256 + 64: 31 full sweeps, tid<64 does one extra.
#pragma unroll 4
    for (int v = tid; v < V4; v += 256) {
        float4 a = r0[v];
        float4 b = r1[v];
        fvec4 r;
        r.x = w0 * a.x + w1 * b.x;
        r.y = w0 * a.y + w1 * b.y;
        r.z = w0 * a.z + w1 * b.z;
        r.w = w0 * a.w + w1 * b.w;
        __builtin_nontemporal_store(r, (fvec4*)orow + v);
    }
}

// ---------------------------------------------------------------------------
// aux: usage + aux loss. One block, 16 waves; wave e reduces the contiguous
// row scores[e][0..T). aux = NE * sum_e u_e*log(u_e), u_e = mean.
// ---------------------------------------------------------------------------
__global__ __launch_bounds__(1024) void aux_kernel(const float* __restrict__ scores,
                                                   float* __restrict__ out)
{
    const int e    = threadIdx.x >> 6;   // wave id = expert
    const int lane = threadIdx.x & 63;

    float s = 0.f;
    const float* row = scores + e * T_TOK;
#pragma unroll
    for (int i = lane; i < T_TOK; i += 64) s += row[i];   // 32 iterations
#pragma unroll
    for (int off = 32; off > 0; off >>= 1) s += __shfl_down(s, off, 64);

    __shared__ float u[NE];
    if (lane == 0) u[e] = s;
    __syncthreads();

    if (threadIdx.x == 0) {
        float aux = 0.f;
#pragma unroll
        for (int i = 0; i < NE; ++i) {
            float ui = u[i] / (float)T_TOK;
            aux += ui * logf(ui);
        }
        out[0] = aux * (float)NE;
    }
}

extern "C" void kernel_launch(void* const* d_in, const int* in_sizes, int n_in,
                              void* d_out, int out_size, void* d_ws, size_t ws_size,
                              hipStream_t stream)
{
    const float* hs = (const float*)d_in[0];   // (T, H)
    const float* gw = (const float*)d_in[1];   // (E, H)
    const float* eb = (const float*)d_in[2];   // (E, V)
    float* out = (float*)d_out;                // T*V floats then 1 aux float

    float* scores = WS_SCORES(d_ws);

    fused_kernel<<<T_TOK, 256, 0, stream>>>((const float4*)hs, (const float4*)gw,
                                            (const float4*)eb, scores, (float4*)out);

    aux_kernel<<<1, 1024, 0, stream>>>(scores, out + (size_t)T_TOK * V_DIM);
}

// Round 2
// 304.375 us; speedup vs baseline: 1.0401x; 1.0401x over previous
//
#include <hip/hip_runtime.h>
#include <math.h>

#define T_TOK 2048
#define H_DIM 2048
#define V_DIM 32000
#define NE    16

typedef float fvec4 __attribute__((ext_vector_type(4)));

// ws layout:
//   scores: NE * T_TOK floats (transposed: scores[e*T_TOK + t])  = 128 KB
//   params: T_TOK float4s, offset 128 KB                          = 32 KB
#define WS_SCORES(ws)  ((float*)(ws))
#define WS_PARAMS(ws)  ((float4*)((char*)(ws) + NE * T_TOK * sizeof(float)))

// ---------------------------------------------------------------------------
// Kernel 1: gating. One block (256 thr) per token. float4 dot products,
// wave shuffle-reduce, LDS combine. Per-token softmax probs written
// transposed to scores[e][t]; aux_kernel reduces them.
// (unchanged from the 293 µs round-0 version)
// ---------------------------------------------------------------------------
__global__ __launch_bounds__(256) void gate_kernel(const float4* __restrict__ hs,
                                                   const float4* __restrict__ gw,
                                                   float* __restrict__ scores,
                                                   float4* __restrict__ params)
{
    const int t   = blockIdx.x;
    const int tid = threadIdx.x;
    const int H4  = H_DIM / 4;   // 512

    float acc[NE];
#pragma unroll
    for (int e = 0; e < NE; ++e) acc[e] = 0.f;

    const float4* hrow = hs + (size_t)t * H4;
#pragma unroll
    for (int i = tid; i < H4; i += 256) {     // 2 iterations
        float4 x = hrow[i];
#pragma unroll
        for (int e = 0; e < NE; ++e) {
            float4 g = gw[e * H4 + i];
            acc[e] += x.x * g.x + x.y * g.y + x.z * g.z + x.w * g.w;
        }
    }

    // 64-lane shuffle reduction per accumulator
#pragma unroll
    for (int e = 0; e < NE; ++e) {
        float v = acc[e];
#pragma unroll
        for (int off = 32; off > 0; off >>= 1) v += __shfl_down(v, off, 64);
        acc[e] = v;
    }

    __shared__ float partial[4][NE];
    __shared__ float exps[NE + 1];   // [NE] = softmax denominator

    const int wave = tid >> 6, lane = tid & 63;
    if (lane == 0) {
#pragma unroll
        for (int e = 0; e < NE; ++e) partial[wave][e] = acc[e];
    }
    __syncthreads();

    if (tid == 0) {
        float logits[NE];
        float m = -INFINITY;
#pragma unroll
        for (int e = 0; e < NE; ++e) {
            logits[e] = partial[0][e] + partial[1][e] + partial[2][e] + partial[3][e];
            m = fmaxf(m, logits[e]);
        }
        float Z = 0.f;
#pragma unroll
        for (int e = 0; e < NE; ++e) { float ex = expf(logits[e] - m); exps[e] = ex; Z += ex; }
        exps[NE] = Z;

        // top-2, strict > ascending scan => lowest index wins ties (jax semantics)
        int i0 = 0; float l0 = logits[0];
#pragma unroll
        for (int e = 1; e < NE; ++e) if (logits[e] > l0) { l0 = logits[e]; i0 = e; }
        int i1 = -1; float l1 = -INFINITY;
#pragma unroll
        for (int e = 0; e < NE; ++e) if (e != i0 && logits[e] > l1) { l1 = logits[e]; i1 = e; }

        float e0 = exps[i0], e1 = exps[i1];
        float inv = 1.f / (e0 + e1);
        params[t] = make_float4(e0 * inv, e1 * inv, __int_as_float(i0), __int_as_float(i1));
    }
    __syncthreads();

    if (tid < NE)
        scores[tid * T_TOK + t] = exps[tid] / exps[NE];
}

// ---------------------------------------------------------------------------
// Kernel 2: bias = w0*eb[i0,:] + w1*eb[i1,:].
// 8 blocks per token, each owning 1000 contiguous float4s (4 stores/thread).
// params[t] is block-uniform -> readfirstlane scalarizes weights + indices,
// so eb row bases are SGPR bases + small VGPR offset, and the dependent
// params->address->load chain is paid once per block, not once per element.
// No div/mod. NT stores keep the 262 MB stream from evicting the 2 MB
// expert_biases working set. Lean kernel => <=64 VGPR => 32 waves/CU.
// ---------------------------------------------------------------------------
#define CHUNKS_PER_TOK 8
#define CHUNK_V4 (V_DIM / 4 / CHUNKS_PER_TOK)   // 1000

__global__ __launch_bounds__(256) void bias_kernel(const float4* __restrict__ eb,
                                                   const float4* __restrict__ params,
                                                   float4* __restrict__ out)
{
    const int V4    = V_DIM / 4;                 // 8000
    const int t     = blockIdx.x >> 3;           // token
    const int chunk = blockIdx.x & 7;
    const int tid   = threadIdx.x;

    float4 p = params[t];                        // uniform address per block
    const int   i0 = __builtin_amdgcn_readfirstlane(__float_as_int(p.z));
    const int   i1 = __builtin_amdgcn_readfirstlane(__float_as_int(p.w));
    const float w0 = __int_as_float(__builtin_amdgcn_readfirstlane(__float_as_int(p.x)));
    const float w1 = __int_as_float(__builtin_amdgcn_readfirstlane(__float_as_int(p.y)));

    const int v0 = chunk * CHUNK_V4;
    const float4* r0 = eb + (size_t)i0 * V4 + v0;     // SGPR base
    const float4* r1 = eb + (size_t)i1 * V4 + v0;     // SGPR base
    fvec4* o = (fvec4*)(out + (size_t)t * V4 + v0);

    // 1000 = 3*256 + 232: 3 full sweeps, tid<232 does one extra.
#pragma unroll 4
    for (int v = tid; v < CHUNK_V4; v += 256) {
        float4 a = r0[v];
        float4 b = r1[v];
        fvec4 r;
        r.x = w0 * a.x + w1 * b.x;
        r.y = w0 * a.y + w1 * b.y;
        r.z = w0 * a.z + w1 * b.z;
        r.w = w0 * a.w + w1 * b.w;
        __builtin_nontemporal_store(r, o + v);
    }
}

// ---------------------------------------------------------------------------
// Kernel 3: usage + aux loss. One block, 16 waves; wave e reduces the
// contiguous row scores[e][0..T). aux = NE * sum_e u_e*log(u_e), u_e = mean.
// ---------------------------------------------------------------------------
__global__ __launch_bounds__(1024) void aux_kernel(const float* __restrict__ scores,
                                                   float* __restrict__ out)
{
    const int e    = threadIdx.x >> 6;   // wave id = expert
    const int lane = threadIdx.x & 63;

    float s = 0.f;
    const float* row = scores + e * T_TOK;
#pragma unroll
    for (int i = lane; i < T_TOK; i += 64) s += row[i];   // 32 iterations
#pragma unroll
    for (int off = 32; off > 0; off >>= 1) s += __shfl_down(s, off, 64);

    __shared__ float u[NE];
    if (lane == 0) u[e] = s;
    __syncthreads();

    if (threadIdx.x == 0) {
        float aux = 0.f;
#pragma unroll
        for (int i = 0; i < NE; ++i) {
            float ui = u[i] / (float)T_TOK;
            aux += ui * logf(ui);
        }
        out[0] = aux * (float)NE;
    }
}

extern "C" void kernel_launch(void* const* d_in, const int* in_sizes, int n_in,
                              void* d_out, int out_size, void* d_ws, size_t ws_size,
                              hipStream_t stream)
{
    const float* hs = (const float*)d_in[0];   // (T, H)
    const float* gw = (const float*)d_in[1];   // (E, H)
    const float* eb = (const float*)d_in[2];   // (E, V)
    float* out = (float*)d_out;                // T*V floats then 1 aux float

    float*  scores = WS_SCORES(d_ws);
    float4* params = WS_PARAMS(d_ws);

    gate_kernel<<<T_TOK, 256, 0, stream>>>((const float4*)hs, (const float4*)gw,
                                           scores, params);

    bias_kernel<<<T_TOK * CHUNKS_PER_TOK, 256, 0, stream>>>((const float4*)eb, params,
                                                            (float4*)out);

    aux_kernel<<<1, 1024, 0, stream>>>(scores, out + (size_t)T_TOK * V_DIM);
}